// Round 8
// baseline (493.682 us; speedup 1.0000x reference)
//
#include <hip/hip_runtime.h>
#include <math.h>

// ---------------------------------------------------------------------------
// Pipeline (all fp32, deterministic):
//  k_init    : threshold table (repeated fp32 add) + zero hist
//  k_conv1   : conv1+bias+relu+maxpool -> pool1 [2048][2880]
//  k_conv2   : conv2+bias+relu+maxpool -> pool2 [2048][800]   (10 waves x 5ch)
//  k_gemmsp  : split-K(4) partial GEMM 128x128/8x8  (fc, then gcn_w)
//  k_fuse    : sum 4 partials (+bias,+relu) -> H / HW
//  k_rowsq   : sq[i] = |H_i|^2
//  k_dist    : dist + histogram, 128x128/8x8 GEMM
//  k_pick    : prefix-scan -> threshold (first cnt >= 615)
//  k_deg     : dinv[i] = rsqrt(1+deg)
//  k_gcn     : sparse GCN aggregate + log_softmax
// R6 evidence: conv2 VGPR=52 (loads interleave fine), 5.9M LDS bank conflicts
// (even img stride -> 16 even banks, 4-way), GEMM 4x2 micro LDS-pipe-bound.
// R7 audit fix: gcn_w split-K kchunk 125 -> 128 (125 gave 500B part origins,
// 500 % 16 != 0 -> misaligned float4 global loads = UB).
// ---------------------------------------------------------------------------

#define NN 2048
#define LL 500
#define NBIN 512

#define KEEP(x) asm volatile("" : "+v"(x))

// ws offsets (in floats)
#define O_POOL1 ((size_t)0)                          // 2048*2880 (reused for GEMM partials)
#define O_POOL2 (O_POOL1 + (size_t)2048*2880)        // 2048*800
#define O_H     (O_POOL2 + (size_t)2048*800)         // 2048*500
#define O_HW    (O_H     + (size_t)2048*500)         // 2048*500
#define O_DIST  (O_HW    + (size_t)2048*500)         // 2048*2048
#define O_SQ    (O_DIST  + (size_t)2048*2048)        // 2048
#define O_TBL   (O_SQ    + 2048)                     // NBIN
#define O_HIST  (O_TBL   + NBIN)                     // NBIN (unsigned)
#define O_THR   (O_HIST  + NBIN)                     // 16
#define O_DINV  (O_THR   + 16)                       // 2048
#define PSZ     ((size_t)2048 * 500)                 // partial buffer stride

__device__ __forceinline__ float4 ldg4_tail(const float* p, int rem) {
    float4 v;
    if (rem >= 4) v = *(const float4*)p;
    else {
        v.x = (rem > 0) ? p[0] : 0.f;
        v.y = (rem > 1) ? p[1] : 0.f;
        v.z = (rem > 2) ? p[2] : 0.f;
        v.w = (rem > 3) ? p[3] : 0.f;
    }
    return v;
}
__device__ __forceinline__ float4 zero4() { float4 v; v.x = v.y = v.z = v.w = 0.f; return v; }

// ---------------------------------------------------------------------------
__global__ void k_init(float* __restrict__ tbl, unsigned* __restrict__ hist) {
    int t = threadIdx.x;
    if (t == 0) {
        float v = 1.7f;
        for (int k = 0; k < NBIN; k++) { tbl[k] = v; v += 0.1f; }
    }
    for (int i = t; i < NBIN; i += 256) hist[i] = 0u;
}

// ---------------------------------------------------------------------------
// conv1: 4 img/block, 512 thr. LDS img stride 785 (ODD -> alternate images on
// odd banks; even strides keep all 64 lanes in the 16 even banks = 4-way).
__global__ __launch_bounds__(512)
void k_conv1(const float* __restrict__ x, const float* __restrict__ w,
             const float* __restrict__ b, float* __restrict__ out) {
    __shared__ float xin[4 * 785];
    int t = threadIdx.x;
    size_t n0 = (size_t)blockIdx.x * 4;
    for (int i = t; i < 784; i += 512) {           // 784 float4 = 4 imgs
        float4 v = ((const float4*)(x + n0 * 784))[i];
        int img = i / 196, off = (i - img * 196) * 4;   // 196 float4 per img
        float* d = &xin[img * 785 + off];
        d[0] = v.x; d[1] = v.y; d[2] = v.z; d[3] = v.w;
    }
    __syncthreads();
    for (int o = t; o < 576; o += 512) {
        int img = o / 144, p = o - img * 144, py = p / 12, px = p - py * 12;
        const float* xi = &xin[img * 785 + (2 * py) * 28 + 2 * px];
        float pt[36];
        #pragma unroll
        for (int r = 0; r < 6; r++)
            #pragma unroll
            for (int c = 0; c < 6; c++) { pt[r * 6 + c] = xi[r * 28 + c]; KEEP(pt[r * 6 + c]); }
        #pragma unroll
        for (int cb = 0; cb < 20; cb += 10) {
            float a0[10], a1[10], a2[10], a3[10];
            #pragma unroll
            for (int c = 0; c < 10; c++) { a0[c] = a1[c] = a2[c] = a3[c] = 0.f; }
            #pragma unroll
            for (int ky = 0; ky < 5; ky++)
                #pragma unroll
                for (int kx = 0; kx < 5; kx++) {
                    float p00 = pt[ky * 6 + kx],       p01 = pt[ky * 6 + kx + 1];
                    float p10 = pt[(ky + 1) * 6 + kx], p11 = pt[(ky + 1) * 6 + kx + 1];
                    #pragma unroll
                    for (int c = 0; c < 10; c++) {
                        float wv = w[(cb + c) * 25 + ky * 5 + kx];
                        a0[c] = fmaf(wv, p00, a0[c]); a1[c] = fmaf(wv, p01, a1[c]);
                        a2[c] = fmaf(wv, p10, a2[c]); a3[c] = fmaf(wv, p11, a3[c]);
                    }
                }
            #pragma unroll
            for (int c = 0; c < 10; c++) {
                float v = fmaxf(fmaxf(a0[c], a1[c]), fmaxf(a2[c], a3[c])) + b[cb + c];
                out[(n0 + img) * 2880 + (size_t)(cb + c) * 144 + p] = fmaxf(v, 0.f);
            }
        }
    }
}

// ---------------------------------------------------------------------------
// conv2: 4 img/block, 640 thr (10 waves), 5 ch/wave (50 = 10x5, no waste).
// LDS img stride 2881 (ODD): kills R6's 5.9M 4-way bank conflicts.
__global__ __launch_bounds__(640)
void k_conv2(const float* __restrict__ in, const float* __restrict__ w,
             const float* __restrict__ b, float* __restrict__ out) {
    __shared__ float s_in[4 * 2881];
    int t = threadIdx.x;
    size_t n0 = (size_t)blockIdx.x * 4;
    for (int img = 0; img < 4; img++) {
        const float4* src = (const float4*)(in + (n0 + img) * 2880);
        float* dst = &s_in[img * 2881];
        for (int i = t; i < 720; i += 640) {
            float4 v = src[i];
            float* d = dst + i * 4;
            d[0] = v.x; d[1] = v.y; d[2] = v.z; d[3] = v.w;
        }
    }
    __syncthreads();
    int lane = t & 63;
    int wv = __builtin_amdgcn_readfirstlane(t >> 6);   // 0..9
    int img = lane >> 4, p = lane & 15, py = p >> 2, px = p & 3;
    int cstart = wv * 5;
    const float* base = &s_in[img * 2881 + (2 * py) * 12 + 2 * px];
    float a0[5], a1[5], a2[5], a3[5];
    #pragma unroll
    for (int c = 0; c < 5; c++) { a0[c] = a1[c] = a2[c] = a3[c] = 0.f; }
    for (int ci = 0; ci < 20; ci++) {
        float pt[36];
        const float* bi = base + ci * 144;
        #pragma unroll
        for (int r = 0; r < 6; r++)
            #pragma unroll
            for (int c = 0; c < 6; c++) { pt[r * 6 + c] = bi[r * 12 + c]; KEEP(pt[r * 6 + c]); }
        #pragma unroll
        for (int ky = 0; ky < 5; ky++)
            #pragma unroll
            for (int kx = 0; kx < 5; kx++) {
                float p00 = pt[ky * 6 + kx],       p01 = pt[ky * 6 + kx + 1];
                float p10 = pt[(ky + 1) * 6 + kx], p11 = pt[(ky + 1) * 6 + kx + 1];
                #pragma unroll
                for (int cc = 0; cc < 5; cc++) {
                    float wt = w[(cstart + cc) * 500 + ci * 25 + ky * 5 + kx];
                    a0[cc] = fmaf(wt, p00, a0[cc]); a1[cc] = fmaf(wt, p01, a1[cc]);
                    a2[cc] = fmaf(wt, p10, a2[cc]); a3[cc] = fmaf(wt, p11, a3[cc]);
                }
            }
    }
    #pragma unroll
    for (int cc = 0; cc < 5; cc++) {
        int c = cstart + cc;
        float v = fmaxf(fmaxf(a0[cc], a1[cc]), fmaxf(a2[cc], a3[cc])) + b[c];
        out[(n0 + img) * 800 + c * 16 + p] = fmaxf(v, 0.f);
    }
}

// ---------------------------------------------------------------------------
// Split-K partial GEMM: 128x128 tile, 256 thr, 8x8 micro (4 b128 / 64 FMA ->
// ~66% VALU ceiling vs 20% for 4x2), BK=32, reg-prefetch dbuf.
// blockIdx.z = K-part; Cpart[p] = A[:, p-range] @ B[p-range, :].
// kchunk MUST make part origins 16B-aligned: kchunk*4 % 16 == 0.
__global__ __launch_bounds__(256)
void k_gemmsp(const float* __restrict__ A, const float* __restrict__ B,
              float* __restrict__ Cpart, int M, int N, int K, int kchunk) {
    __shared__ __align__(16) float As[32][132];
    __shared__ __align__(16) float Bs[32][132];
    int t = threadIdx.x;
    int m0 = blockIdx.y * 128, n0 = blockIdx.x * 128;
    int part = blockIdx.z;
    int kbeg = part * kchunk;
    int kend = kbeg + kchunk; if (kend > K) kend = K;
    float* Cp = Cpart + (size_t)part * M * N;

    int ar = t >> 3, akc = (t & 7) * 4;     // A loader: rows ar+32g, k-cols akc..+3
    int bkr = t >> 4, bc = (t & 15) * 4;    // B loader: k-rows bkr,+16; cols bc,+64
    int ty = t >> 4, tx = t & 15;
    float acc[8][8] = {};
    float4 pa[4], pb[4];

#define SP_LOAD(k0) do {                                                        \
        int rem = kend - ((k0) + akc);                                          \
        pa[0] = ldg4_tail(&A[(size_t)(m0 + ar)      * K + (k0) + akc], rem);    \
        pa[1] = ldg4_tail(&A[(size_t)(m0 + ar + 32) * K + (k0) + akc], rem);    \
        pa[2] = ldg4_tail(&A[(size_t)(m0 + ar + 64) * K + (k0) + akc], rem);    \
        pa[3] = ldg4_tail(&A[(size_t)(m0 + ar + 96) * K + (k0) + akc], rem);    \
        int rn0 = N - (n0 + bc), rn1 = N - (n0 + bc + 64);                      \
        pb[0] = ((k0) + bkr < kend)                                             \
              ? ldg4_tail(&B[(size_t)((k0) + bkr) * N + n0 + bc], rn0) : zero4(); \
        pb[1] = ((k0) + bkr < kend)                                             \
              ? ldg4_tail(&B[(size_t)((k0) + bkr) * N + n0 + bc + 64], rn1) : zero4(); \
        pb[2] = ((k0) + bkr + 16 < kend)                                        \
              ? ldg4_tail(&B[(size_t)((k0) + bkr + 16) * N + n0 + bc], rn0) : zero4(); \
        pb[3] = ((k0) + bkr + 16 < kend)                                        \
              ? ldg4_tail(&B[(size_t)((k0) + bkr + 16) * N + n0 + bc + 64], rn1) : zero4(); \
    } while (0)

#define SP_STORE() do {                                                         \
        for (int g = 0; g < 4; g++) {                                           \
            As[akc + 0][ar + 32 * g] = pa[g].x; As[akc + 1][ar + 32 * g] = pa[g].y; \
            As[akc + 2][ar + 32 * g] = pa[g].z; As[akc + 3][ar + 32 * g] = pa[g].w; \
        }                                                                       \
        *(float4*)&Bs[bkr][bc]           = pb[0];                               \
        *(float4*)&Bs[bkr][bc + 64]      = pb[1];                               \
        *(float4*)&Bs[bkr + 16][bc]      = pb[2];                               \
        *(float4*)&Bs[bkr + 16][bc + 64] = pb[3];                               \
    } while (0)

    SP_LOAD(kbeg); SP_STORE(); __syncthreads();
    for (int k0 = kbeg; k0 < kend; k0 += 32) {
        bool more = (k0 + 32) < kend;
        if (more) SP_LOAD(k0 + 32);
        #pragma unroll
        for (int kk = 0; kk < 32; kk++) {
            float4 A0 = *(const float4*)&As[kk][ty * 8];
            float4 A1 = *(const float4*)&As[kk][ty * 8 + 4];
            float4 B0 = *(const float4*)&Bs[kk][tx * 4];
            float4 B1 = *(const float4*)&Bs[kk][64 + tx * 4];
            float av[8] = {A0.x, A0.y, A0.z, A0.w, A1.x, A1.y, A1.z, A1.w};
            float bv[8] = {B0.x, B0.y, B0.z, B0.w, B1.x, B1.y, B1.z, B1.w};
            #pragma unroll
            for (int i = 0; i < 8; i++)
                #pragma unroll
                for (int j = 0; j < 8; j++) acc[i][j] = fmaf(av[i], bv[j], acc[i][j]);
        }
        __syncthreads();
        if (more) { SP_STORE(); __syncthreads(); }
    }
#undef SP_LOAD
#undef SP_STORE

    #pragma unroll
    for (int ii = 0; ii < 8; ii++) {
        int row = m0 + ty * 8 + ii;
        #pragma unroll
        for (int g = 0; g < 2; g++) {
            int c0 = n0 + g * 64 + tx * 4;
            if (c0 + 3 < N) {
                float4 vv;
                vv.x = acc[ii][g * 4 + 0]; vv.y = acc[ii][g * 4 + 1];
                vv.z = acc[ii][g * 4 + 2]; vv.w = acc[ii][g * 4 + 3];
                *(float4*)&Cp[(size_t)row * N + c0] = vv;
            } else {
                #pragma unroll
                for (int j = 0; j < 4; j++)
                    if (c0 + j < N) Cp[(size_t)row * N + c0 + j] = acc[ii][g * 4 + j];
            }
        }
    }
}

// ---------------------------------------------------------------------------
// Fuse 4 partials: out = (relu?)(p0+p1+p2+p3 (+bias[col]))
__global__ __launch_bounds__(256)
void k_fuse(const float* __restrict__ parts, float* __restrict__ out,
            const float* __restrict__ bias, int relu) {
    int i4 = blockIdx.x * 256 + threadIdx.x;          // 256000 float4-groups
    size_t off = (size_t)i4 * 4;
    float4 s = *(const float4*)&parts[off];
    #pragma unroll
    for (int p = 1; p < 4; p++) {
        float4 v = *(const float4*)&parts[p * PSZ + off];
        s.x += v.x; s.y += v.y; s.z += v.z; s.w += v.w;
    }
    float vv[4] = {s.x, s.y, s.z, s.w};
    if (bias) {
        int base = i4 * 4;
        int col0 = base - (base / LL) * LL;
        #pragma unroll
        for (int j = 0; j < 4; j++) {
            int c = col0 + j; if (c >= LL) c -= LL;
            vv[j] += bias[c];
        }
    }
    if (relu) {
        #pragma unroll
        for (int j = 0; j < 4; j++) vv[j] = fmaxf(vv[j], 0.f);
    }
    float4 o; o.x = vv[0]; o.y = vv[1]; o.z = vv[2]; o.w = vv[3];
    *(float4*)&out[off] = o;
}

// ---------------------------------------------------------------------------
__global__ __launch_bounds__(256)
void k_rowsq(const float* __restrict__ H, float* __restrict__ sq) {
    int t = threadIdx.x, lane = t & 63, wv = t >> 6;
    int row = blockIdx.x * 4 + wv;
    const float* h = &H[(size_t)row * LL];
    float s = 0.f;
    for (int j = lane; j < LL; j += 64) { float v = h[j]; s = fmaf(v, v, s); }
    #pragma unroll
    for (int o = 32; o > 0; o >>= 1) s += __shfl_down(s, o, 64);
    if (lane == 0) sq[row] = s;
}

// ---------------------------------------------------------------------------
// dist GEMM: 128x128 tile, 256 thr, 8x8 micro, BK=32, reg-prefetch dbuf.
// Grid (16,16)=256. dist = sqrt(max(sq_i+sq_j-2*acc,0)) + histogram.
__global__ __launch_bounds__(256)
void k_dist(const float* __restrict__ Hm, float* __restrict__ C,
            const float* __restrict__ sq, const float* __restrict__ tbl_g,
            unsigned* __restrict__ hist_g) {
    __shared__ __align__(16) float As[32][132];
    __shared__ __align__(16) float Bs[32][132];
    __shared__ float tbl_s[NBIN];
    __shared__ unsigned hist_s[NBIN];
    const int K = LL, N = NN;
    int t = threadIdx.x;
    int m0 = blockIdx.y * 128, n0 = blockIdx.x * 128;
    for (int i = t; i < NBIN; i += 256) { tbl_s[i] = tbl_g[i]; hist_s[i] = 0u; }
    float acc[8][8] = {};
    int lr = t >> 3, lkc = (t & 7) * 4;
    int ty = t >> 4, tx = t & 15;
    float4 pa[4], pb[4];

#define D_LOAD(k0) do {                                                         \
        int rem = K - ((k0) + lkc);                                             \
        pa[0] = ldg4_tail(&Hm[(size_t)(m0 + lr)      * K + (k0) + lkc], rem);   \
        pa[1] = ldg4_tail(&Hm[(size_t)(m0 + lr + 32) * K + (k0) + lkc], rem);   \
        pa[2] = ldg4_tail(&Hm[(size_t)(m0 + lr + 64) * K + (k0) + lkc], rem);   \
        pa[3] = ldg4_tail(&Hm[(size_t)(m0 + lr + 96) * K + (k0) + lkc], rem);   \
        pb[0] = ldg4_tail(&Hm[(size_t)(n0 + lr)      * K + (k0) + lkc], rem);   \
        pb[1] = ldg4_tail(&Hm[(size_t)(n0 + lr + 32) * K + (k0) + lkc], rem);   \
        pb[2] = ldg4_tail(&Hm[(size_t)(n0 + lr + 64) * K + (k0) + lkc], rem);   \
        pb[3] = ldg4_tail(&Hm[(size_t)(n0 + lr + 96) * K + (k0) + lkc], rem);   \
    } while (0)

#define D_STORE() do {                                                          \
        for (int g = 0; g < 4; g++) {                                           \
            As[lkc + 0][lr + 32 * g] = pa[g].x; As[lkc + 1][lr + 32 * g] = pa[g].y; \
            As[lkc + 2][lr + 32 * g] = pa[g].z; As[lkc + 3][lr + 32 * g] = pa[g].w; \
            Bs[lkc + 0][lr + 32 * g] = pb[g].x; Bs[lkc + 1][lr + 32 * g] = pb[g].y; \
            Bs[lkc + 2][lr + 32 * g] = pb[g].z; Bs[lkc + 3][lr + 32 * g] = pb[g].w; \
        }                                                                       \
    } while (0)

    D_LOAD(0); D_STORE(); __syncthreads();
    for (int k0 = 0; k0 < K; k0 += 32) {
        bool more = (k0 + 32) < K;
        if (more) D_LOAD(k0 + 32);
        #pragma unroll
        for (int kk = 0; kk < 32; kk++) {
            float4 A0 = *(const float4*)&As[kk][ty * 8];
            float4 A1 = *(const float4*)&As[kk][ty * 8 + 4];
            float4 B0 = *(const float4*)&Bs[kk][tx * 4];
            float4 B1 = *(const float4*)&Bs[kk][64 + tx * 4];
            float av[8] = {A0.x, A0.y, A0.z, A0.w, A1.x, A1.y, A1.z, A1.w};
            float bv[8] = {B0.x, B0.y, B0.z, B0.w, B1.x, B1.y, B1.z, B1.w};
            #pragma unroll
            for (int i = 0; i < 8; i++)
                #pragma unroll
                for (int j = 0; j < 8; j++) acc[i][j] = fmaf(av[i], bv[j], acc[i][j]);
        }
        __syncthreads();
        if (more) { D_STORE(); __syncthreads(); }
    }
#undef D_LOAD
#undef D_STORE

    #pragma unroll
    for (int ii = 0; ii < 8; ii++) {
        int i = m0 + ty * 8 + ii;
        float sqi = sq[i];
        #pragma unroll
        for (int g = 0; g < 2; g++) {
            int c0 = n0 + g * 64 + tx * 4;
            float4 sqj = *(const float4*)&sq[c0];
            float sqjv[4] = {sqj.x, sqj.y, sqj.z, sqj.w};
            float dd[4];
            #pragma unroll
            for (int j = 0; j < 4; j++) {
                int col = c0 + j;
                float d2 = sqi + sqjv[j] - 2.0f * acc[ii][g * 4 + j];
                float d = sqrtf(fmaxf(d2, 0.f));
                dd[j] = d;
                if (col != i) {
                    int bb = (int)ceilf((d - 1.7f) * 10.0f);
                    bb = bb < 0 ? 0 : (bb > NBIN - 1 ? NBIN - 1 : bb);
                    while (bb > 0 && d < tbl_s[bb - 1]) --bb;
                    while (bb < NBIN - 1 && d >= tbl_s[bb]) ++bb;
                    if (d < tbl_s[bb]) atomicAdd(&hist_s[bb], 1u);
                }
            }
            float4 dv; dv.x = dd[0]; dv.y = dd[1]; dv.z = dd[2]; dv.w = dd[3];
            *(float4*)&C[(size_t)i * N + c0] = dv;
        }
    }
    __syncthreads();
    for (int idx = t; idx < NBIN; idx += 256)
        if (hist_s[idx]) atomicAdd(&hist_g[idx], hist_s[idx]);
}

// ---------------------------------------------------------------------------
__global__ __launch_bounds__(256)
void k_pick(const unsigned* __restrict__ hist, const float* __restrict__ tbl,
            float* __restrict__ thrbuf) {
    __shared__ unsigned ps[256];
    __shared__ int sel;
    int t = threadIdx.x;
    if (t == 0) sel = NBIN - 1;
    unsigned v0 = hist[2 * t], v1 = hist[2 * t + 1];
    unsigned s = v0 + v1;
    ps[t] = s;
    __syncthreads();
    for (int o = 1; o < 256; o <<= 1) {
        unsigned add = (t >= o) ? ps[t - o] : 0u;
        __syncthreads();
        ps[t] += add;
        __syncthreads();
    }
    unsigned c = ps[t] - s;
    int f = -1;
    c += v0; if (c >= 615u) f = 2 * t;
    else { c += v1; if (c >= 615u) f = 2 * t + 1; }
    if (f >= 0) atomicMin(&sel, f);
    __syncthreads();
    if (t == 0) thrbuf[0] = tbl[sel];
}

// ---------------------------------------------------------------------------
__global__ __launch_bounds__(256)
void k_deg(const float* __restrict__ dist, const float* __restrict__ thrbuf,
           float* __restrict__ dinv) {
    int t = threadIdx.x, lane = t & 63, wv = t >> 6;
    int row = blockIdx.x * 4 + wv;
    float thr = thrbuf[0];
    const float4* dr4 = (const float4*)&dist[(size_t)row * NN];
    int cnt = 0;
    #pragma unroll
    for (int bq = 0; bq < 8; bq++) {
        int i4 = bq * 64 + lane;
        float4 v = dr4[i4];
        int j = i4 * 4;
        cnt += (v.x < thr && j + 0 != row) ? 1 : 0;
        cnt += (v.y < thr && j + 1 != row) ? 1 : 0;
        cnt += (v.z < thr && j + 2 != row) ? 1 : 0;
        cnt += (v.w < thr && j + 3 != row) ? 1 : 0;
    }
    #pragma unroll
    for (int o = 32; o > 0; o >>= 1) cnt += __shfl_down(cnt, o, 64);
    if (lane == 0) dinv[row] = 1.0f / sqrtf((float)(cnt + 1));
}

// ---------------------------------------------------------------------------
__global__ __launch_bounds__(256)
void k_gcn(const float* __restrict__ dist, const float* __restrict__ thrbuf,
           const float* __restrict__ dinv, const float* __restrict__ HW,
           const float* __restrict__ bias, float* __restrict__ outp) {
    __shared__ int nbr[2048];
    __shared__ float ndv[2048];
    __shared__ unsigned cnts[256];
    __shared__ float red[16];
    int t = threadIdx.x, lane = t & 63, wv = t >> 6;
    int i = blockIdx.x;
    float thr = thrbuf[0];
    const float* dr = &dist[(size_t)i * NN];
    float4 q0 = *(const float4*)&dr[t * 8];
    float4 q1 = *(const float4*)&dr[t * 8 + 4];
    float dv[8] = {q0.x, q0.y, q0.z, q0.w, q1.x, q1.y, q1.z, q1.w};
    unsigned lc = 0;
    #pragma unroll
    for (int q = 0; q < 8; q++) lc += (dv[q] < thr && (t * 8 + q) != i) ? 1u : 0u;
    cnts[t] = lc;
    __syncthreads();
    for (int o = 1; o < 256; o <<= 1) {
        unsigned add = (t >= o) ? cnts[t - o] : 0u;
        __syncthreads();
        cnts[t] += add;
        __syncthreads();
    }
    unsigned pos = cnts[t] - lc;
    int nn = (int)cnts[255];
    #pragma unroll
    for (int q = 0; q < 8; q++) {
        int j = t * 8 + q;
        if (dv[q] < thr && j != i) { nbr[pos] = j; ndv[pos] = dinv[j]; pos++; }
    }
    __syncthreads();
    float di = dinv[i];
    float v0, v1 = -1e30f, mx;
    {
        int d = t;
        float s = di * HW[(size_t)i * LL + d];
        for (int m = 0; m < nn; m++) s += ndv[m] * HW[(size_t)nbr[m] * LL + d];
        v0 = di * s + bias[d];
        mx = v0;
    }
    if (t + 256 < LL) {
        int d = t + 256;
        float s = di * HW[(size_t)i * LL + d];
        for (int m = 0; m < nn; m++) s += ndv[m] * HW[(size_t)nbr[m] * LL + d];
        v1 = di * s + bias[d];
        mx = fmaxf(mx, v1);
    }
    #pragma unroll
    for (int o = 32; o > 0; o >>= 1) mx = fmaxf(mx, __shfl_down(mx, o, 64));
    if (lane == 0) red[wv] = mx;
    __syncthreads();
    mx = fmaxf(fmaxf(red[0], red[1]), fmaxf(red[2], red[3]));
    float es = expf(v0 - mx) + ((t + 256 < LL) ? expf(v1 - mx) : 0.f);
    #pragma unroll
    for (int o = 32; o > 0; o >>= 1) es += __shfl_down(es, o, 64);
    if (lane == 0) red[8 + wv] = es;
    __syncthreads();
    float lse = logf(red[8] + red[9] + red[10] + red[11]);
    outp[(size_t)i * LL + t] = v0 - mx - lse;
    if (t + 256 < LL) outp[(size_t)i * LL + t + 256] = v1 - mx - lse;
}

// ---------------------------------------------------------------------------
extern "C" void kernel_launch(void* const* d_in, const int* in_sizes, int n_in,
                              void* d_out, int out_size, void* d_ws, size_t ws_size,
                              hipStream_t stream) {
    (void)in_sizes; (void)n_in; (void)out_size; (void)ws_size;
    const float* x   = (const float*)d_in[0];
    const float* c1w = (const float*)d_in[1];
    const float* c1b = (const float*)d_in[2];
    const float* c2w = (const float*)d_in[3];
    const float* c2b = (const float*)d_in[4];
    const float* fcw = (const float*)d_in[5];
    const float* fcb = (const float*)d_in[6];
    const float* gw  = (const float*)d_in[7];
    const float* gb  = (const float*)d_in[8];

    float* ws = (float*)d_ws;
    float* pool1 = ws + O_POOL1;     // also: 4x split-K partial buffers (4.1M floats <= 5.9M)
    float* pool2 = ws + O_POOL2;
    float* H     = ws + O_H;
    float* HWp   = ws + O_HW;
    float* distm = ws + O_DIST;
    float* sqv   = ws + O_SQ;
    float* tbl   = ws + O_TBL;
    unsigned* hist = (unsigned*)(ws + O_HIST);
    float* thr   = ws + O_THR;
    float* dinv  = ws + O_DINV;
    float* part  = pool1;

    k_init<<<1, 256, 0, stream>>>(tbl, hist);
    k_conv1<<<512, 512, 0, stream>>>(x, c1w, c1b, pool1);
    k_conv2<<<512, 640, 0, stream>>>(pool1, c2w, c2b, pool2);
    // pool1 dead from here; reuse as split-K partials.
    k_gemmsp<<<dim3(4, 16, 4), 256, 0, stream>>>(pool2, fcw, part, 2048, 500, 800, 200);
    k_fuse<<<1000, 256, 0, stream>>>(part, H, fcb, 1);
    k_gemmsp<<<dim3(4, 16, 4), 256, 0, stream>>>(H, gw, part, 2048, 500, 500, 128);
    k_fuse<<<1000, 256, 0, stream>>>(part, HWp, nullptr, 0);
    k_rowsq<<<512, 256, 0, stream>>>(H, sqv);
    k_dist<<<dim3(16, 16), 256, 0, stream>>>(H, distm, sqv, tbl, hist);
    k_pick<<<1, 256, 0, stream>>>(hist, tbl, thr);
    k_deg<<<512, 256, 0, stream>>>(distm, thr, dinv);
    k_gcn<<<2048, 256, 0, stream>>>(distm, thr, dinv, HWp, gb, (float*)d_out);
}